// Round 6
// baseline (450.498 us; speedup 1.0000x reference)
//
#include <hip/hip_runtime.h>
#include <stdint.h>

#define BB 32
#define CC 2048
#define NPIX 49
#define KPAD 64
#define K9 18432      // CC*9 (k = tap*2048 + ci, tap-major)
#define ZROWS 2624    // 32*81 interior+halo rows + 32 guard rows (zero)
#define NP 1792       // dense n padded (14*128)
#define CONV_SPLITK 4

typedef __bf16 bf16;
typedef __bf16 bf16x2 __attribute__((ext_vector_type(2)));
typedef __bf16 bf16x4 __attribute__((ext_vector_type(4)));
typedef __bf16 bf16x8 __attribute__((ext_vector_type(8)));
typedef float f32x2 __attribute__((ext_vector_type(2)));
typedef float f32x4 __attribute__((ext_vector_type(4)));
typedef uint32_t u32x4 __attribute__((ext_vector_type(4)));

#define MFMA(a,b,c) __builtin_amdgcn_mfma_f32_16x16x32_bf16(a,b,c,0,0,0)
#define GLOAD_LDS(g, l) __builtin_amdgcn_global_load_lds( \
    (const __attribute__((address_space(1))) void*)(g),   \
    (__attribute__((address_space(3))) void*)(l), 16, 0, 0)

// ---------- prep: x -> xb [B][C][64] bf16 ----------
__global__ void prep_xb_kernel(const float* __restrict__ x, bf16* __restrict__ xb) {
    uint32_t idx = blockIdx.x * 256u + threadIdx.x;
    uint32_t n = idx & 63u, bc = idx >> 6;
    float v = (n < 49u) ? x[bc * 49u + n] : 0.f;
    xb[idx] = (bf16)v;
}

// ---------- prep: x -> xbT [B][64][C] bf16 ----------
__global__ void prep_xbT_kernel(const float* __restrict__ x, bf16* __restrict__ xbT) {
    uint32_t idx = blockIdx.x * 256u + threadIdx.x;
    uint32_t c = idx & 2047u, n = (idx >> 11) & 63u, b = idx >> 17;
    float v = (n < 49u) ? x[(b * 2048u + c) * 49u + n] : 0.f;
    xbT[idx] = (bf16)v;
}

// ---------- prep: conv_w [co][ci][3][3] f32 -> Wr [co][t][ci] bf16 ----------
__global__ void castw_kernel(const float* __restrict__ cw, bf16* __restrict__ Wr) {
    uint32_t t = blockIdx.x * 256u + threadIdx.x;
    uint32_t q = t & 511u, co = t >> 9;
    uint32_t ci0 = q * 4u;
    const float* src = cw + ((size_t)co * 2048u + ci0) * 9u;
    float v[4][9];
#pragma unroll
    for (int c = 0; c < 4; c++)
#pragma unroll
        for (int tt = 0; tt < 9; tt++) v[c][tt] = src[c * 9 + tt];
    bf16* dst = Wr + (size_t)co * K9 + ci0;
#pragma unroll
    for (int tt = 0; tt < 9; tt++) {
        bf16x4 o;
        o[0] = (bf16)v[0][tt]; o[1] = (bf16)v[1][tt];
        o[2] = (bf16)v[2][tt]; o[3] = (bf16)v[3][tt];
        *(bf16x4*)(dst + (size_t)tt * 2048u) = o;
    }
}

// ---------- prep: zero YpT ----------
__global__ void zero_ypt_kernel(u32x4* __restrict__ YpT) {
    YpT[blockIdx.x * 256u + threadIdx.x] = (u32x4){0, 0, 0, 0};
}

// ---------- attn partial: bilinear -> exp -> partial Y (unnormalized) over half the d range ----------
// grid 1024 = 8 xcd x (4 batch x 16 cblk x 2 half): 4 blocks/CU fully resident.
// Partials are additive (no online max needed): Y = (Y0+Y1)/(s0+s1).
__global__ __launch_bounds__(256, 4) void attn_kernel(
    const bf16* __restrict__ xb, const bf16* __restrict__ xbT,
    float* __restrict__ part, float* __restrict__ RS)
{
    __shared__ __align__(16) char smem_raw[34816];
    bf16 (*Plds)[32][136] = reinterpret_cast<bf16(*)[32][136]>(smem_raw);
    float (*Tlds)[132]    = reinterpret_cast<float(*)[132]>(smem_raw);   // [64 n][128+4 c] f32
    const int tid = threadIdx.x;
    const int w = tid >> 6, l = tid & 63;
    const int lhi = l >> 4, llo = l & 15;
    const uint32_t g = blockIdx.x;
    const int xcd = g & 7, inner = g >> 3;       // [0,128)
    const int b = xcd + (inner >> 5) * 8;        // 4 batches per XCD (L2-resident)
    const int cblk = (inner >> 1) & 15;
    const int h = inner & 1;
    const int c0 = cblk * 128 + w * 32;
    const bf16* xbB = xb + (size_t)b * CC * KPAD;
    const bf16* xbTB = xbT + (size_t)b * KPAD * CC;

    bf16x8 aQ[2][2];
#pragma unroll
    for (int cf = 0; cf < 2; cf++)
#pragma unroll
        for (int kk = 0; kk < 2; kk++)
            aQ[cf][kk] = *(const bf16x8*)(xbB + (uint32_t)(c0 + cf * 16 + llo) * KPAD + kk * 32 + lhi * 8);

    f32x4 accY[2][4];
#pragma unroll
    for (int cf = 0; cf < 2; cf++)
#pragma unroll
        for (int nf = 0; nf < 4; nf++) accY[cf][nf] = (f32x4){0, 0, 0, 0};
    float rowsum[2][4] = {};

    const float kES = -0.029442756956917622f;    // -log2(e)/49

    for (int dt = h * 8; dt < h * 8 + 8; dt++) {
        const int d0 = dt * 128;
        f32x4 accS[2][8];
#pragma unroll
        for (int cf = 0; cf < 2; cf++)
#pragma unroll
            for (int df = 0; df < 8; df++) accS[cf][df] = (f32x4){0, 0, 0, 0};
#pragma unroll
        for (int kk = 0; kk < 2; kk++) {
#pragma unroll
            for (int df = 0; df < 8; df++) {
                bf16x8 bK = *(const bf16x8*)(xbB + (uint32_t)(d0 + df * 16 + llo) * KPAD + kk * 32 + lhi * 8);
                accS[0][df] = MFMA(aQ[0][kk], bK, accS[0][df]);
                accS[1][df] = MFMA(aQ[1][kk], bK, accS[1][df]);
            }
        }
#pragma unroll
        for (int cf = 0; cf < 2; cf++)
#pragma unroll
            for (int df = 0; df < 8; df++)
#pragma unroll
                for (int r = 0; r < 4; r++) {
                    float p = __builtin_amdgcn_exp2f(accS[cf][df][r] * kES);  // arg in [-0.5,0.07]: safe
                    rowsum[cf][r] += p;
                    Plds[w][cf * 16 + lhi * 4 + r][df * 16 + llo] = (bf16)p;
                }
        // Plds is wave-private: no barrier, compiler handles lgkmcnt
#pragma unroll
        for (int kk2 = 0; kk2 < 4; kk2++) {
            bf16x8 aP[2];
#pragma unroll
            for (int cf = 0; cf < 2; cf++)
                aP[cf] = *(const bf16x8*)&Plds[w][cf * 16 + llo][kk2 * 32 + lhi * 8];
#pragma unroll
            for (int nf = 0; nf < 4; nf++) {
                bf16x8 bV = *(const bf16x8*)(xbTB + (uint32_t)(nf * 16 + llo) * CC + d0 + kk2 * 32 + lhi * 8);
                accY[0][nf] = MFMA(aP[0], bV, accY[0][nf]);
                accY[1][nf] = MFMA(aP[1], bV, accY[1][nf]);
            }
        }
    }
    // partial rowsum: reduce over the 16 llo lanes; store raw (no normalize)
#pragma unroll
    for (int cf = 0; cf < 2; cf++)
#pragma unroll
        for (int r = 0; r < 4; r++) {
            float s = rowsum[cf][r];
            s += __shfl_xor(s, 1);
            s += __shfl_xor(s, 2);
            s += __shfl_xor(s, 4);
            s += __shfl_xor(s, 8);
            if (llo == 0)
                RS[((size_t)b * 2 + h) * CC + c0 + cf * 16 + lhi * 4 + r] = s;
        }
    __syncthreads();   // Tlds aliases all waves' Plds
#pragma unroll
    for (int cf = 0; cf < 2; cf++)
#pragma unroll
        for (int nf = 0; nf < 4; nf++)
#pragma unroll
            for (int r = 0; r < 4; r++)
                Tlds[nf * 16 + llo][w * 32 + cf * 16 + lhi * 4 + r] = accY[cf][nf][r];
    __syncthreads();
    // write part[(b*16+cblk)*2+h][n 64][c 128] f32, 8B/lane coalesced
    float* pY = part + (size_t)(((b * 16 + cblk) * 2 + h)) * 8192;
    const int col2 = (tid & 63) * 2;
#pragma unroll
    for (int rr = 0; rr < 16; rr++) {
        int row = rr * 4 + w;
        f32x2 v = { Tlds[row][col2], Tlds[row][col2 + 1] };
        *(f32x2*)(pY + row * 128 + col2) = v;
    }
}

// ---------- combine: YpT[b][sp][c] = (Y0+Y1)/(s0+s1), bf16 ----------
__global__ void combine_kernel(const float* __restrict__ part, const float* __restrict__ RS,
                               bf16* __restrict__ YpT)
{
    const int tid = threadIdx.x;
    const int b = blockIdx.x >> 4, cblk = blockIdx.x & 15;
    const int col2 = (tid & 63) * 2;
    const float* p0 = part + (size_t)(((b * 16 + cblk) * 2 + 0)) * 8192;
    const float* p1 = p0 + 8192;
    f32x2 s0 = *(const f32x2*)(RS + ((size_t)b * 2 + 0) * CC + cblk * 128 + col2);
    f32x2 s1 = *(const f32x2*)(RS + ((size_t)b * 2 + 1) * CC + cblk * 128 + col2);
    float inv0 = 1.0f / (s0[0] + s1[0]);
    float inv1 = 1.0f / (s0[1] + s1[1]);
#pragma unroll
    for (int rr = 0; rr < 13; rr++) {
        int row = rr * 4 + (tid >> 6);
        if (row < NPIX) {
            f32x2 a = *(const f32x2*)(p0 + row * 128 + col2);
            f32x2 c = *(const f32x2*)(p1 + row * 128 + col2);
            bf16x2 o;
            o[0] = (bf16)((a[0] + c[0]) * inv0);
            o[1] = (bf16)((a[1] + c[1]) * inv1);
            int i = row / 7, j = row % 7;
            int sp = (i + 1) * 9 + (j + 1);
            *(bf16x2*)(YpT + ((size_t)b * 81 + sp) * CC + cblk * 128 + col2) = o;
        }
    }
}

// ---------- direct conv GEMM: M=2048(co), N=1792, K=18432, splitK=4 ----------
// 896 blocks (3.5/CU), 512 thr = 8 waves of 64co x 32n. T2 both-sides XOR swizzle.
__global__ __launch_bounds__(512, 4) void conv_kernel(
    const bf16* __restrict__ Wr, const bf16* __restrict__ YpT, float* __restrict__ partials)
{
    __shared__ bf16 Asub[128 * 64];
    __shared__ bf16 Bsub[128 * 64];
    const int tid = threadIdx.x;
    const int w = tid >> 6, l = tid & 63;
    const int lhi = l >> 4, llo = l & 15;
    const int wm = w >> 2, wn = w & 3;

    uint32_t g = blockIdx.x;
    uint32_t xcd = g & 7u, inner = g >> 3;       // inner in [0,112)
    uint32_t pairIdx = xcd * 8u + inner / 14u;   // [0,64): (z,mt) grouped per XCD
    uint32_t nt = inner % 14u;
    uint32_t z = pairIdx >> 4, mt = pairIdx & 15u;

    uint32_t kb16 = tid & 7u;
    uint32_t row0 = tid >> 3;
    uint32_t srcK = (kb16 ^ (row0 & 7u)) << 3;

    const bf16* gaBase[2];
    const bf16* gbBase[2];
#pragma unroll
    for (int i = 0; i < 2; i++) {
        uint32_t row = row0 + (uint32_t)i * 64u;
        gaBase[i] = Wr + (size_t)(mt * 128u + row) * K9 + (size_t)z * 4608u + srcK;
        uint32_t n = nt * 128u + row;
        uint32_t rowIdx;
        if (n < 1568u) {
            uint32_t b = n / 49u, p = n % 49u;
            uint32_t i2 = p / 7u, j2 = p % 7u;
            rowIdx = b * 81u + (i2 + 1u) * 9u + (j2 + 1u);
        } else rowIdx = 2602u;
        gbBase[i] = YpT + (size_t)rowIdx * 2048u + srcK;
    }

    f32x4 acc[4][2];
#pragma unroll
    for (int fm = 0; fm < 4; fm++)
#pragma unroll
        for (int fn = 0; fn < 2; fn++) acc[fm][fn] = (f32x4){0, 0, 0, 0};

    for (int ktl = 0; ktl < 72; ktl++) {
        uint32_t kt = z * 72u + (uint32_t)ktl;
        uint32_t tap = kt >> 5, ci0 = (kt & 31u) << 6;
        int tapoff = (int)(tap / 3u) * 9 + (int)(tap % 3u) - 10;
        uint32_t kbA = (uint32_t)ktl * 64u;
#pragma unroll
        for (int i = 0; i < 2; i++) {
            GLOAD_LDS(gaBase[i] + kbA, (char*)Asub + i * 8192 + tid * 16);
            GLOAD_LDS(gbBase[i] + (int)ci0 + tapoff * 2048, (char*)Bsub + i * 8192 + tid * 16);
        }
        __syncthreads();
#pragma unroll
        for (int kk = 0; kk < 2; kk++) {
            bf16x8 af[4], bfr[2];
#pragma unroll
            for (int f = 0; f < 4; f++) {
                uint32_t r = (uint32_t)(wm * 64 + f * 16 + llo);
                uint32_t bo = r * 128u + ((((uint32_t)(kk * 4 + lhi)) ^ (r & 7u)) << 4);
                af[f] = *(const bf16x8*)((const char*)Asub + bo);
            }
#pragma unroll
            for (int f = 0; f < 2; f++) {
                uint32_t r = (uint32_t)(wn * 32 + f * 16 + llo);
                uint32_t bo = r * 128u + ((((uint32_t)(kk * 4 + lhi)) ^ (r & 7u)) << 4);
                bfr[f] = *(const bf16x8*)((const char*)Bsub + bo);
            }
#pragma unroll
            for (int fm = 0; fm < 4; fm++)
#pragma unroll
                for (int fn = 0; fn < 2; fn++)
                    acc[fm][fn] = MFMA(af[fm], bfr[fn], acc[fm][fn]);
        }
        __syncthreads();
    }
    float* pz = partials + (size_t)z * 2048u * NP;
    uint32_t co0 = mt * 128u + (uint32_t)(wm * 64 + lhi * 4);
    uint32_t n0 = nt * 128u + (uint32_t)(wn * 32 + llo);
#pragma unroll
    for (int fm = 0; fm < 4; fm++)
#pragma unroll
        for (int fn = 0; fn < 2; fn++)
#pragma unroll
            for (int r = 0; r < 4; r++)
                pz[(size_t)(co0 + fm * 16u + r) * NP + (n0 + fn * 16u)] = acc[fm][fn][r];
}

// ---------- reduce: out = sum_z partials + bias + residual ----------
__global__ void reduce_kernel(const float* __restrict__ partials, const float* __restrict__ x,
                              const float* __restrict__ cb, float* __restrict__ out)
{
    uint32_t idx = blockIdx.x * 256u + threadIdx.x;
    uint32_t p = idx % 49u;
    uint32_t c = (idx / 49u) & 2047u;
    uint32_t b = idx / (49u * 2048u);
    uint32_t n = b * 49u + p;
    size_t base = (size_t)c * NP + n;
    float s = cb[c] + x[idx];
#pragma unroll
    for (int zz = 0; zz < CONV_SPLITK; zz++) s += partials[(size_t)zz * 2048u * NP + base];
    out[idx] = s;
}

extern "C" void kernel_launch(void* const* d_in, const int* in_sizes, int n_in,
                              void* d_out, int out_size, void* d_ws, size_t ws_size,
                              hipStream_t stream) {
    (void)in_sizes; (void)n_in; (void)out_size; (void)ws_size;
    const float* x = (const float*)d_in[0];
    const float* cw = (const float*)d_in[1];
    const float* cb = (const float*)d_in[2];
    float* out = (float*)d_out;
    char* ws = (char*)d_ws;

    bf16* xb   = (bf16*)(ws);                    //   8,388,608 B
    bf16* xbT  = (bf16*)(ws + 8388608);          //   8,388,608 B
    bf16* Wr   = (bf16*)(ws + 16777216);         //  75,497,472 B
    bf16* YpT  = (bf16*)(ws + 92274688);         //  10,747,904 B
    float* part = (float*)(ws + 103022592);      //  33,554,432 B (attn Y partials)
    float* RS   = (float*)(ws + 136577024);      //     524,288 B (attn rowsum partials)
    float* partials = (float*)(ws + 137101312);  //  58,720,256 B (conv, total 195,821,568)

    prep_xb_kernel<<<16384, 256, 0, stream>>>(x, xb);
    prep_xbT_kernel<<<16384, 256, 0, stream>>>(x, xbT);
    castw_kernel<<<4096, 256, 0, stream>>>(cw, Wr);
    zero_ypt_kernel<<<2624, 256, 0, stream>>>((u32x4*)YpT);
    attn_kernel<<<1024, 256, 0, stream>>>(xb, xbT, part, RS);
    combine_kernel<<<512, 256, 0, stream>>>(part, RS, YpT);
    conv_kernel<<<896, 512, 0, stream>>>(Wr, YpT, partials);
    reduce_kernel<<<12544, 256, 0, stream>>>(partials, x, cb, out);
}

// Round 7
// 267.341 us; speedup vs baseline: 1.6851x; 1.6851x over previous
//
#include <hip/hip_runtime.h>
#include <stdint.h>

#define BB 32
#define CC 2048
#define NPIX 49
#define KPAD 64
#define K9 18432      // CC*9 (k = tap*2048 + ci, tap-major)
#define ZROWS 2624    // 32*81 interior+halo rows + 32 guard rows (zero)
#define NP 1792       // dense n padded (14*128)

typedef __bf16 bf16;
typedef __bf16 bf16x2 __attribute__((ext_vector_type(2)));
typedef __bf16 bf16x4 __attribute__((ext_vector_type(4)));
typedef __bf16 bf16x8 __attribute__((ext_vector_type(8)));
typedef float f32x4 __attribute__((ext_vector_type(4)));
typedef uint32_t u32x4 __attribute__((ext_vector_type(4)));

#define MFMA(a,b,c) __builtin_amdgcn_mfma_f32_16x16x32_bf16(a,b,c,0,0,0)
#define GLOAD_LDS(g, l) __builtin_amdgcn_global_load_lds( \
    (const __attribute__((address_space(1))) void*)(g),   \
    (__attribute__((address_space(3))) void*)(l), 16, 0, 0)

// ---------- prep: x -> xb [B][C][64] bf16 ----------
__global__ void prep_xb_kernel(const float* __restrict__ x, bf16* __restrict__ xb) {
    uint32_t idx = blockIdx.x * 256u + threadIdx.x;
    uint32_t n = idx & 63u, bc = idx >> 6;
    float v = (n < 49u) ? x[bc * 49u + n] : 0.f;
    xb[idx] = (bf16)v;
}

// ---------- prep: x -> xbT [B][64][C] bf16 ----------
__global__ void prep_xbT_kernel(const float* __restrict__ x, bf16* __restrict__ xbT) {
    uint32_t idx = blockIdx.x * 256u + threadIdx.x;
    uint32_t c = idx & 2047u, n = (idx >> 11) & 63u, b = idx >> 17;
    float v = (n < 49u) ? x[(b * 2048u + c) * 49u + n] : 0.f;
    xbT[idx] = (bf16)v;
}

// ---------- prep: conv_w [co][ci][3][3] f32 -> Wr [co][t][ci] bf16 ----------
__global__ void castw_kernel(const float* __restrict__ cw, bf16* __restrict__ Wr) {
    uint32_t t = blockIdx.x * 256u + threadIdx.x;
    uint32_t q = t & 511u, co = t >> 9;
    uint32_t ci0 = q * 4u;
    const float* src = cw + ((size_t)co * 2048u + ci0) * 9u;
    float v[4][9];
#pragma unroll
    for (int c = 0; c < 4; c++)
#pragma unroll
        for (int tt = 0; tt < 9; tt++) v[c][tt] = src[c * 9 + tt];
    bf16* dst = Wr + (size_t)co * K9 + ci0;
#pragma unroll
    for (int tt = 0; tt < 9; tt++) {
        bf16x4 o;
        o[0] = (bf16)v[0][tt]; o[1] = (bf16)v[1][tt];
        o[2] = (bf16)v[2][tt]; o[3] = (bf16)v[3][tt];
        *(bf16x4*)(dst + (size_t)tt * 2048u) = o;
    }
}

// ---------- prep: zero YpT ----------
__global__ void zero_ypt_kernel(u32x4* __restrict__ YpT) {
    YpT[blockIdx.x * 256u + threadIdx.x] = (u32x4){0, 0, 0, 0};
}

// ---------- fused bilinear -> softmax -> Y, LDS-staged K/V tiles ----------
// 512 blocks (4 batches/XCD), 4 waves x 32 c-rows. Per dt: stage Ktile[128][64]
// + Vtile[64][128] via global_load_lds (contiguous rows, shared by all waves;
// kills the 64-line/wave stride gathers that made R5 cache-request-bound),
// T2 both-sides XOR swizzle on the stride-128B/256B fragment reads.
__global__ __launch_bounds__(256, 2) void attn_kernel(
    const bf16* __restrict__ xb, const bf16* __restrict__ xbT, bf16* __restrict__ YpT)
{
    __shared__ __align__(16) char smem[67584];
    bf16* Ktile = (bf16*)smem;                         // [128 d][64 k]   swizzled
    bf16* Vtile = (bf16*)(smem + 16384);               // [64 n][128 d]   swizzled
    bf16 (*Plds)[32][136] = reinterpret_cast<bf16(*)[32][136]>(smem + 32768);
    bf16 (*Tlds)[132] = reinterpret_cast<bf16(*)[132]>(smem);  // epilogue alias of K/V

    const int tid = threadIdx.x;
    const int w = tid >> 6, l = tid & 63;
    const int lhi = l >> 4, llo = l & 15;
    const uint32_t g = blockIdx.x;
    const int xcd = g & 7, inner = g >> 3;
    const int b = xcd + (inner >> 4) * 8;              // 4 batches per XCD
    const int cblk = inner & 15;
    const int c0 = cblk * 128 + w * 32;
    const bf16* xbB = xb + (size_t)b * CC * KPAD;
    const bf16* xbTB = xbT + (size_t)b * KPAD * CC;

    // hoisted A-frags (one-time gather)
    bf16x8 aQ[2][2];
#pragma unroll
    for (int cf = 0; cf < 2; cf++)
#pragma unroll
        for (int kk = 0; kk < 2; kk++)
            aQ[cf][kk] = *(const bf16x8*)(xbB + (uint32_t)(c0 + cf * 16 + llo) * KPAD + kk * 32 + lhi * 8);

    // staging geometry (loop-invariant). K: row=i*32+(tid>>3), slot=tid&7.
    // V: row=i*16+(tid>>4), slot=tid&15. srcSlot = slot ^ (row&7) (both-sides swizzle).
    const uint32_t rowK = tid >> 3;                    // + i*32 (i*32 % 8 == 0)
    const uint32_t srcKoff = (uint32_t)(((tid & 7u) ^ (rowK & 7u)) << 3);
    const bf16* kSrc = xbB + (size_t)rowK * KPAD + srcKoff;     // + (d0+i*32)*64
    const uint32_t rowV = tid >> 4;                    // + i*16 (i*16 % 8 == 0)
    const uint32_t srcVoff = (uint32_t)(((tid & 15u) ^ (rowV & 7u)) << 3);
    const bf16* vSrc = xbTB + (size_t)rowV * CC + srcVoff;      // + d0

    f32x4 accY[2][4];
#pragma unroll
    for (int cf = 0; cf < 2; cf++)
#pragma unroll
        for (int nf = 0; nf < 4; nf++) accY[cf][nf] = (f32x4){0, 0, 0, 0};
    float rowsum[2][4] = {};

    const float kES = -0.029442756956917622f;          // -log2(e)/49

    for (int dt = 0; dt < 16; dt++) {
        const int d0 = dt * 128;
#pragma unroll
        for (int i = 0; i < 4; i++) {
            GLOAD_LDS(kSrc + (size_t)(d0 + i * 32) * KPAD, (char*)Ktile + i * 4096 + tid * 16);
            GLOAD_LDS(vSrc + d0 + (size_t)i * 16 * CC,     (char*)Vtile + i * 4096 + tid * 16);
        }
        __syncthreads();                               // drains vmcnt before barrier

        f32x4 accS[2][8];
#pragma unroll
        for (int cf = 0; cf < 2; cf++)
#pragma unroll
            for (int df = 0; df < 8; df++) accS[cf][df] = (f32x4){0, 0, 0, 0};
#pragma unroll
        for (int kk = 0; kk < 2; kk++) {
#pragma unroll
            for (int df = 0; df < 8; df++) {
                uint32_t r = (uint32_t)(df * 16 + llo);
                bf16x8 bK = *(const bf16x8*)((const char*)Ktile + r * 128u +
                                             ((((uint32_t)(kk * 4 + lhi)) ^ (r & 7u)) << 4));
                accS[0][df] = MFMA(aQ[0][kk], bK, accS[0][df]);
                accS[1][df] = MFMA(aQ[1][kk], bK, accS[1][df]);
            }
        }
#pragma unroll
        for (int cf = 0; cf < 2; cf++)
#pragma unroll
            for (int df = 0; df < 8; df++)
#pragma unroll
                for (int r = 0; r < 4; r++) {
                    float p = __builtin_amdgcn_exp2f(accS[cf][df][r] * kES);
                    rowsum[cf][r] += p;
                    Plds[w][cf * 16 + lhi * 4 + r][df * 16 + llo] = (bf16)p;
                }
        // Plds is wave-private: compiler-ordered via lgkmcnt, no barrier
#pragma unroll
        for (int kk2 = 0; kk2 < 4; kk2++) {
            bf16x8 aP[2];
#pragma unroll
            for (int cf = 0; cf < 2; cf++)
                aP[cf] = *(const bf16x8*)&Plds[w][cf * 16 + llo][kk2 * 32 + lhi * 8];
#pragma unroll
            for (int nf = 0; nf < 4; nf++) {
                uint32_t r = (uint32_t)(nf * 16 + llo);
                bf16x8 bV = *(const bf16x8*)((const char*)Vtile + r * 256u +
                                             ((((uint32_t)(kk2 * 4 + lhi)) ^ (r & 7u)) << 4));
                accY[0][nf] = MFMA(aP[0], bV, accY[0][nf]);
                accY[1][nf] = MFMA(aP[1], bV, accY[1][nf]);
            }
        }
        __syncthreads();                               // all waves done before restage
    }
#pragma unroll
    for (int cf = 0; cf < 2; cf++)
#pragma unroll
        for (int r = 0; r < 4; r++) {
            float s = rowsum[cf][r];
            s += __shfl_xor(s, 1);
            s += __shfl_xor(s, 2);
            s += __shfl_xor(s, 4);
            s += __shfl_xor(s, 8);
            rowsum[cf][r] = 1.0f / s;
        }
    // Tlds aliases Ktile/Vtile; final loop barrier already passed, but PV reads of
    // THIS iteration are wave-local and done (register deps). One barrier for safety:
    __syncthreads();
#pragma unroll
    for (int cf = 0; cf < 2; cf++)
#pragma unroll
        for (int nf = 0; nf < 4; nf++)
#pragma unroll
            for (int r = 0; r < 4; r++) {
                int n = nf * 16 + llo;
                int cl = w * 32 + cf * 16 + lhi * 4 + r;
                Tlds[n][cl] = (bf16)(accY[cf][nf][r] * rowsum[cf][r]);
            }
    __syncthreads();
#pragma unroll
    for (int rr = 0; rr < 13; rr++) {
        int row = rr * 4 + (tid >> 6);
        if (row < NPIX) {
            int i = row / 7, j = row % 7;
            int sp = (i + 1) * 9 + (j + 1);
            int col2 = tid & 63;
            uint32_t val = *(const uint32_t*)&Tlds[row][col2 * 2];
            *(uint32_t*)(YpT + ((size_t)b * 81 + sp) * CC + cblk * 128 + col2 * 2) = val;
        }
    }
}

// ---------- direct conv GEMM: M=2048(co), N=1792, K=18432, splitK=2 (R5 config) ----------
__global__ __launch_bounds__(512, 4) void conv_kernel(
    const bf16* __restrict__ Wr, const bf16* __restrict__ YpT, float* __restrict__ partials)
{
    __shared__ bf16 Asub[128 * 64];
    __shared__ bf16 Bsub[128 * 64];
    const int tid = threadIdx.x;
    const int w = tid >> 6, l = tid & 63;
    const int lhi = l >> 4, llo = l & 15;
    const int wm = w >> 2, wn = w & 3;

    uint32_t g = blockIdx.x;
    uint32_t xcd = g & 7u, inner = g >> 3;
    uint32_t pairIdx = xcd * 4u + inner / 14u;
    uint32_t nt = inner % 14u;
    uint32_t z = pairIdx >> 4, mt = pairIdx & 15u;

    uint32_t kb16 = tid & 7u;
    uint32_t row0 = tid >> 3;
    uint32_t srcK = (kb16 ^ (row0 & 7u)) << 3;

    const bf16* gaBase[2];
    const bf16* gbBase[2];
#pragma unroll
    for (int i = 0; i < 2; i++) {
        uint32_t row = row0 + (uint32_t)i * 64u;
        gaBase[i] = Wr + (size_t)(mt * 128u + row) * K9 + (size_t)z * 9216u + srcK;
        uint32_t n = nt * 128u + row;
        uint32_t rowIdx;
        if (n < 1568u) {
            uint32_t b = n / 49u, p = n % 49u;
            uint32_t i2 = p / 7u, j2 = p % 7u;
            rowIdx = b * 81u + (i2 + 1u) * 9u + (j2 + 1u);
        } else rowIdx = 2602u;
        gbBase[i] = YpT + (size_t)rowIdx * 2048u + srcK;
    }

    f32x4 acc[4][2];
#pragma unroll
    for (int fm = 0; fm < 4; fm++)
#pragma unroll
        for (int fn = 0; fn < 2; fn++) acc[fm][fn] = (f32x4){0, 0, 0, 0};

    for (int ktl = 0; ktl < 144; ktl++) {
        uint32_t kt = z * 144u + (uint32_t)ktl;
        uint32_t tap = kt >> 5, ci0 = (kt & 31u) << 6;
        int tapoff = (int)(tap / 3u) * 9 + (int)(tap % 3u) - 10;
        uint32_t kbA = (uint32_t)ktl * 64u;
#pragma unroll
        for (int i = 0; i < 2; i++) {
            GLOAD_LDS(gaBase[i] + kbA, (char*)Asub + i * 8192 + tid * 16);
            GLOAD_LDS(gbBase[i] + (int)ci0 + tapoff * 2048, (char*)Bsub + i * 8192 + tid * 16);
        }
        __syncthreads();
#pragma unroll
        for (int kk = 0; kk < 2; kk++) {
            bf16x8 af[4], bfr[2];
#pragma unroll
            for (int f = 0; f < 4; f++) {
                uint32_t r = (uint32_t)(wm * 64 + f * 16 + llo);
                uint32_t bo = r * 128u + ((((uint32_t)(kk * 4 + lhi)) ^ (r & 7u)) << 4);
                af[f] = *(const bf16x8*)((const char*)Asub + bo);
            }
#pragma unroll
            for (int f = 0; f < 2; f++) {
                uint32_t r = (uint32_t)(wn * 32 + f * 16 + llo);
                uint32_t bo = r * 128u + ((((uint32_t)(kk * 4 + lhi)) ^ (r & 7u)) << 4);
                bfr[f] = *(const bf16x8*)((const char*)Bsub + bo);
            }
#pragma unroll
            for (int fm = 0; fm < 4; fm++)
#pragma unroll
                for (int fn = 0; fn < 2; fn++)
                    acc[fm][fn] = MFMA(af[fm], bfr[fn], acc[fm][fn]);
        }
        __syncthreads();
    }
    float* pz = partials + (size_t)z * 2048u * NP;
    uint32_t co0 = mt * 128u + (uint32_t)(wm * 64 + lhi * 4);
    uint32_t n0 = nt * 128u + (uint32_t)(wn * 32 + llo);
#pragma unroll
    for (int fm = 0; fm < 4; fm++)
#pragma unroll
        for (int fn = 0; fn < 2; fn++)
#pragma unroll
            for (int r = 0; r < 4; r++)
                pz[(size_t)(co0 + fm * 16u + r) * NP + (n0 + fn * 16u)] = acc[fm][fn][r];
}

// ---------- reduce: out = p0 + p1 + bias + residual ----------
__global__ void reduce_kernel(const float* __restrict__ partials, const float* __restrict__ x,
                              const float* __restrict__ cb, float* __restrict__ out)
{
    uint32_t idx = blockIdx.x * 256u + threadIdx.x;
    uint32_t p = idx % 49u;
    uint32_t c = (idx / 49u) & 2047u;
    uint32_t b = idx / (49u * 2048u);
    uint32_t n = b * 49u + p;
    size_t base = (size_t)c * NP + n;
    out[idx] = cb[c] + x[idx] + partials[base] + partials[(size_t)2048u * NP + base];
}

extern "C" void kernel_launch(void* const* d_in, const int* in_sizes, int n_in,
                              void* d_out, int out_size, void* d_ws, size_t ws_size,
                              hipStream_t stream) {
    (void)in_sizes; (void)n_in; (void)out_size; (void)ws_size;
    const float* x = (const float*)d_in[0];
    const float* cw = (const float*)d_in[1];
    const float* cb = (const float*)d_in[2];
    float* out = (float*)d_out;
    char* ws = (char*)d_ws;

    bf16* xb   = (bf16*)(ws);                    //   8,388,608 B
    bf16* xbT  = (bf16*)(ws + 8388608);          //   8,388,608 B
    bf16* Wr   = (bf16*)(ws + 16777216);         //  75,497,472 B
    bf16* YpT  = (bf16*)(ws + 92274688);         //  10,747,904 B
    float* partials = (float*)(ws + 103022592);  //  29,360,128 B (total 132,382,720)

    prep_xb_kernel<<<16384, 256, 0, stream>>>(x, xb);
    prep_xbT_kernel<<<16384, 256, 0, stream>>>(x, xbT);
    castw_kernel<<<4096, 256, 0, stream>>>(cw, Wr);
    zero_ypt_kernel<<<2624, 256, 0, stream>>>((u32x4*)YpT);
    attn_kernel<<<512, 256, 0, stream>>>(xb, xbT, YpT);
    conv_kernel<<<448, 512, 0, stream>>>(Wr, YpT, partials);
    reduce_kernel<<<12544, 256, 0, stream>>>(partials, x, cb, out);
}